// Round 10
// baseline (149.593 us; speedup 1.0000x reference)
//
#include <hip/hip_runtime.h>
#include <hip/hip_bf16.h>

// Problem constants
#define B_    2
#define T_    2048
#define C_    1024
#define H_    16
#define D_    64
#define SRCL_ 128

typedef short  short8 __attribute__((ext_vector_type(8)));   // 8 bf16 (4 VGPRs)
typedef short  short4_t __attribute__((ext_vector_type(4))); // 4 bf16 (2 VGPRs)
typedef float  f32x4  __attribute__((ext_vector_type(4)));
typedef unsigned short ushort4_t __attribute__((ext_vector_type(4)));

// Q pre-scale: 0.125 (1/sqrt(64)) * log2(e) so attn can use raw v_exp_f32 (2^x)
#define QSCALE 0.18033688011112042f

__device__ inline unsigned short f2bf(float f) {
    union { float f; unsigned u; } v; v.f = f;
    unsigned r = v.u + 0x7FFFu + ((v.u >> 16) & 1u);   // RNE
    return (unsigned short)(r >> 16);
}

#if __has_builtin(__builtin_amdgcn_exp2f)
#define EXP2F(x) __builtin_amdgcn_exp2f(x)
#else
#define EXP2F(x) exp2f(x)
#endif

// 16x16x16 bf16 MFMA (K=16). Preprocessor-guarded so the HOST pass (where
// __has_builtin on amdgcn builtins is false) still compiles: it gets the
// benign `return c` body, which is never executed on host.
__device__ __forceinline__ f32x4 mfma16_bf16(short4_t a, short4_t b, f32x4 c) {
#if __has_builtin(__builtin_amdgcn_mfma_f32_16x16x16bf16_1k)
    return __builtin_amdgcn_mfma_f32_16x16x16bf16_1k(a, b, c, 0, 0, 0);
#elif __has_builtin(__builtin_amdgcn_mfma_f32_16x16x16_bf16)
    return __builtin_amdgcn_mfma_f32_16x16x16_bf16(a, b, c, 0, 0, 0);
#else
    (void)a; (void)b;
    return c;   // host pass only
#endif
}

// async global->LDS DMA, 16B per lane; LDS dest = uniform base + lane*16
__device__ __forceinline__ void async_ld16(const void* g, void* l) {
    __builtin_amdgcn_global_load_lds(
        (const __attribute__((address_space(1))) unsigned int*)g,
        (__attribute__((address_space(3))) unsigned int*)l, 16, 0, 0);
}

// ---------------------------------------------------------------------------
// Kernel 1: fp32 -> bf16 conversion of x and the three weight matrices.
// ---------------------------------------------------------------------------
__global__ __launch_bounds__(256) void convert_all(
        const float* __restrict__ x,
        const float* __restrict__ wq,
        const float* __restrict__ wk,
        const float* __restrict__ wv,
        unsigned short* __restrict__ xb,
        unsigned short* __restrict__ wb)
{
    const int NX = (B_ * T_ * C_) / 4;
    const int NW = (C_ * C_) / 4;
    int i = blockIdx.x * 256 + threadIdx.x;
    const float4* src;
    ushort4_t* dst;
    if (i < NX)               { src = (const float4*)x;  dst = (ushort4_t*)xb;                }
    else if (i < NX + NW)     { src = (const float4*)wq; dst = (ushort4_t*)wb;                i -= NX; }
    else if (i < NX + 2*NW)   { src = (const float4*)wk; dst = (ushort4_t*)(wb + C_*C_);      i -= NX + NW; }
    else                      { src = (const float4*)wv; dst = (ushort4_t*)(wb + 2*C_*C_);    i -= NX + 2*NW; }
    float4 v = src[i];
    ushort4_t o;
    o.x = f2bf(v.x); o.y = f2bf(v.y); o.z = f2bf(v.z); o.w = f2bf(v.w);
    dst[i] = o;
}

// ---------------------------------------------------------------------------
// Kernel 2: fused QKV projection GEMM (unchanged from round 8).
//  outputs chunk-tiled per (bh, 64-t-tile), 8KB tiles:
//    Q,K: [d-chunk 0..7][t 0..63][8 d]   (Q pre-scaled by QSCALE)
//    V:   [t-chunk 0..7][d 0..63][8 t]
// ---------------------------------------------------------------------------
__global__ __launch_bounds__(256, 4) void gemm_qkv(
        const unsigned short* __restrict__ xb,   // [4096,1024]
        const unsigned short* __restrict__ wb,   // [3072,1024]
        const float* __restrict__ bq,
        const float* __restrict__ bk,
        const float* __restrict__ bv,
        unsigned short* __restrict__ qo,
        unsigned short* __restrict__ kt,
        unsigned short* __restrict__ vt)
{
    __shared__ __align__(16) unsigned short uni[16640];      // 33,280 B

    const int tid  = threadIdx.x;
    const int wave = tid >> 6;
    const int lane = tid & 63;
    const int lane15 = lane & 15;
    const int quad   = lane >> 4;
    const int wm = wave >> 1;
    const int wn = wave & 1;
    const int m0 = (blockIdx.x & 31) * 128;
    const int n0 = (blockIdx.x >> 5) * 128;

    f32x4 acc[4][4];
#pragma unroll
    for (int mi = 0; mi < 4; ++mi)
#pragma unroll
        for (int ni = 0; ni < 4; ++ni)
            acc[mi][ni] = (f32x4){0.f, 0.f, 0.f, 0.f};

    const int c0   = wave * 2;
    const int rowi0 = 16 * c0 + (lane >> 2);
    const int rowi1 = 16 * (c0 + 1) + (lane >> 2);
    const int col8 = (lane & 3) * 8;

    const unsigned short* xrow0 = &xb[(m0 + rowi0) * 1024 + col8];
    const unsigned short* xrow1 = &xb[(m0 + rowi1) * 1024 + col8];
    const unsigned short* wrow0 = &wb[(n0 + rowi0) * 1024 + col8];
    const unsigned short* wrow1 = &wb[(n0 + rowi1) * 1024 + col8];

    async_ld16(xrow0, &uni[c0 * 512]);
    async_ld16(xrow1, &uni[(c0 + 1) * 512]);
    async_ld16(wrow0, &uni[4096 + c0 * 512]);
    async_ld16(wrow1, &uni[4096 + (c0 + 1) * 512]);

    for (int it = 0; it < 32; ++it) {
        __asm__ volatile("s_waitcnt vmcnt(0)\n\ts_barrier" ::: "memory");

        if (it + 1 < 32) {
            const int k1 = (it + 1) * 32;
            unsigned short* nb = &uni[((it + 1) & 1) * 8192];
            async_ld16(xrow0 + k1, &nb[c0 * 512]);
            async_ld16(xrow1 + k1, &nb[(c0 + 1) * 512]);
            async_ld16(wrow0 + k1, &nb[4096 + c0 * 512]);
            async_ld16(wrow1 + k1, &nb[4096 + (c0 + 1) * 512]);
        }

        const unsigned short* As = &uni[(it & 1) * 8192];
        const unsigned short* Bs = As + 4096;

        short8 a[4], bf[4];
#pragma unroll
        for (int mi = 0; mi < 4; ++mi)
            a[mi] = *(const short8*)&As[(wm * 64 + mi * 16 + lane15) * 32 + quad * 8];
#pragma unroll
        for (int ni = 0; ni < 4; ++ni)
            bf[ni] = *(const short8*)&Bs[(wn * 64 + ni * 16 + lane15) * 32 + quad * 8];
#pragma unroll
        for (int mi = 0; mi < 4; ++mi)
#pragma unroll
            for (int ni = 0; ni < 4; ++ni)
                acc[mi][ni] = __builtin_amdgcn_mfma_f32_16x16x32_bf16(a[mi], bf[ni], acc[mi][ni], 0, 0, 0);
    }

    __syncthreads();

    const int colbase = n0 + wn * 64;
    const int which   = colbase >> 10;
    const int jj0     = colbase & 1023;
    const int h       = jj0 >> 6;
    const int rowbase = m0 + wm * 64;
    const int bidx    = rowbase >> 11;
    const int t0      = rowbase & 2047;
    const size_t bh   = (size_t)bidx * H_ + h;
    const float* bias_p = (which == 0 ? bq : (which == 1 ? bk : bv)) + jj0;
    const float oscale  = (which == 0) ? QSCALE : 1.0f;

    unsigned short* stage = &uni[wave * 4160];

    if (which != 2) {
#pragma unroll
        for (int ni = 0; ni < 4; ++ni) {
            const float bias = bias_p[ni * 16 + lane15];
            const int d = ni * 16 + lane15;
            const int dbase = (d >> 3) * 520 + (d & 7);
#pragma unroll
            for (int mi = 0; mi < 4; ++mi)
#pragma unroll
                for (int r = 0; r < 4; ++r) {
                    const int tt = mi * 16 + quad * 4 + r;
                    stage[dbase + tt * 8] = f2bf((acc[mi][ni][r] + bias) * oscale);
                }
        }
    } else {
#pragma unroll
        for (int ni = 0; ni < 4; ++ni) {
            const float bias = bias_p[ni * 16 + lane15];
            const int d = ni * 16 + lane15;
#pragma unroll
            for (int mi = 0; mi < 4; ++mi)
#pragma unroll
                for (int r = 0; r < 4; ++r) {
                    const int tt = mi * 16 + quad * 4 + r;
                    stage[(tt >> 3) * 520 + d * 8 + (tt & 7)] = f2bf(acc[mi][ni][r] + bias);
                }
        }
    }

    unsigned short* gdst =
        (which == 0 ? qo : (which == 1 ? kt : vt)) + bh * (size_t)(T_ * D_) + (t0 >> 6) * 4096;

#pragma unroll
    for (int c = 0; c < 8; ++c) {
        *(short8*)&gdst[(c * 64 + lane) * 8] = *(const short8*)&stage[c * 520 + lane * 8];
    }
}

// ---------------------------------------------------------------------------
// Kernel 3: flash attention, key-split across waves.
// Block = (bh, 64 q-rows); wave s owns keys s*16..s*16+15 of EVERY 64-key
// tile -> each wave reads only 2KB K + 2KB V per tile (4x LDS cut).
// P stays in registers: S^T from 16x16x32 lands in 16x16x16 B-operand layout
// (k = quad*4+reg), so PV uses 16x16x16 MFMA with packed bf16 directly.
// Per-wave partial O (64q x 64d) merged once per block via pairwise LDS tree.
// ---------------------------------------------------------------------------
__global__ __launch_bounds__(256, 3) void attn(
        const unsigned short* __restrict__ qg,   // chunk-tiled Q (pre-scaled)
        const unsigned short* __restrict__ kg,   // chunk-tiled K
        const unsigned short* __restrict__ vg,   // chunk-tiled V
        float* __restrict__ out)                 // [B,T,C] fp32
{
    __shared__ __align__(16) unsigned short stage[2][8192];  // DMA bufs / merge scratch
    __shared__ float Lb[4][4][16];                           // per-wave l partials

    const int tid  = threadIdx.x;
    const int s    = tid >> 6;                   // wave = key slice 0..3
    const int lane = tid & 63;
    const int lane15 = lane & 15;
    const int quad   = lane >> 4;

    const int bh = blockIdx.x & 31;
    const int a  = 31 - (blockIdx.x >> 5);       // heavy q-blocks first
    const int b  = bh >> 4;
    const int h  = bh & 15;

    const unsigned short* Q  = qg + (size_t)bh * T_ * D_;
    const unsigned short* KT = kg + (size_t)bh * T_ * D_;
    const unsigned short* VT = vg + (size_t)bh * T_ * D_;

    // Q fragments for ALL 64 q rows (B-operand of 16x16x32), from chunk-tiled Q
    short8 qf[4][2];
#pragma unroll
    for (int nq = 0; nq < 4; ++nq) {
        const int row = nq * 16 + lane15;
        qf[nq][0] = *(const short8*)&Q[a * 4096 + quad * 512 + row * 8];
        qf[nq][1] = *(const short8*)&Q[a * 4096 + (4 + quad) * 512 + row * 8];
    }

    f32x4 o_acc[4][4];                           // [dd][nq] = O^T[d][q] partial
#pragma unroll
    for (int dd = 0; dd < 4; ++dd)
#pragma unroll
        for (int nq = 0; nq < 4; ++nq)
            o_acc[dd][nq] = (f32x4){0.f, 0.f, 0.f, 0.f};
    float l_part[4] = {0.f, 0.f, 0.f, 0.f};

    const int ntiles = min(a + 3, 32);
    const int ib = s * 4;
    const int loff = lane * 8;

    // prologue: tile 0 -> buf 0
#pragma unroll
    for (int c = 0; c < 4; ++c) {
        const int i = ib + c;
        const unsigned short* src = (i < 8) ? &KT[i * 512 + loff]
                                            : &VT[(i - 8) * 512 + loff];
        async_ld16(src, &stage[0][i * 512]);
    }

    for (int it = 0; it < ntiles; ++it) {
        __asm__ volatile("s_waitcnt vmcnt(0)\n\ts_barrier" ::: "memory");

        if (it + 1 < ntiles) {
            unsigned short* nb = &stage[(it + 1) & 1][0];
            const size_t tb = (size_t)(it + 1) * 4096;
#pragma unroll
            for (int c = 0; c < 4; ++c) {
                const int i = ib + c;
                const unsigned short* src = (i < 8) ? &KT[tb + i * 512 + loff]
                                                    : &VT[tb + (i - 8) * 512 + loff];
                async_ld16(src, &nb[i * 512]);
            }
        }

        const unsigned short* sb = &stage[it & 1][0];

        // K slice (16 keys) A-frags: A[m=key=lane15][k=quad*8+j (d)]
        const int krow = s * 16 + lane15;
        const short8 kf0 = *(const short8*)&sb[quad * 512 + krow * 8];
        const short8 kf1 = *(const short8*)&sb[(4 + quad) * 512 + krow * 8];

        // V slice A-frags for 16x16x16: A[m=d=lane15][k=quad*4+j (key)]
        // chunk-tiled V: chunk ct holds keys ct*8..ct*8+7 -> elem [ct*512+d*8+(t&7)]
        short4_t vf[4];
        {
            const int tkey = s * 16 + quad * 4;           // first of 4 keys
            const int ct   = tkey >> 3;
            const int t7   = tkey & 7;
#pragma unroll
            for (int dd = 0; dd < 4; ++dd) {
                const int d = dd * 16 + lane15;
                vf[dd] = *(const short4_t*)&sb[4096 + ct * 512 + d * 8 + t7];
            }
        }

        // ---- S^T slice = K_s Q^T : sv[nq][r] = S^T[key=s*16+quad*4+r][q=nq*16+lane15]
        f32x4 sv[4];
#pragma unroll
        for (int nq = 0; nq < 4; ++nq) {
            f32x4 t = (f32x4){0.f, 0.f, 0.f, 0.f};
            t = __builtin_amdgcn_mfma_f32_16x16x32_bf16(kf0, qf[nq][0], t, 0, 0, 0);
            t = __builtin_amdgcn_mfma_f32_16x16x32_bf16(kf1, qf[nq][1], t, 0, 0, 0);
            sv[nq] = t;
        }

        // masking: only tile it == a+2 can violate key <= q + 128
        if (it == a + 2) {
            const int keyb = it * 64 + s * 16 + quad * 4;
#pragma unroll
            for (int nq = 0; nq < 4; ++nq) {
                const int limit = a * 64 + nq * 16 + lane15 + SRCL_;
#pragma unroll
                for (int r = 0; r < 4; ++r)
                    if (keyb + r > limit) sv[nq][r] = -INFINITY;
            }
        }

        // exp -> P stays in registers as 16x16x16 B-frags; accumulate l
        short4_t pf[4];
#pragma unroll
        for (int nq = 0; nq < 4; ++nq) {
            const float p0 = EXP2F(sv[nq][0]);
            const float p1 = EXP2F(sv[nq][1]);
            const float p2 = EXP2F(sv[nq][2]);
            const float p3 = EXP2F(sv[nq][3]);
            l_part[nq] += (p0 + p1) + (p2 + p3);
            const unsigned u0 = __float_as_uint(p0) + 0x8000u;
            const unsigned u1 = __float_as_uint(p1) + 0x8000u;
            const unsigned u2 = __float_as_uint(p2) + 0x8000u;
            const unsigned u3 = __float_as_uint(p3) + 0x8000u;
            union { uint2 u; short4_t s4; } pk;
            pk.u.x = __builtin_amdgcn_perm(u1, u0, 0x07060302);
            pk.u.y = __builtin_amdgcn_perm(u3, u2, 0x07060302);
            pf[nq] = pk.s4;
        }

        // ---- O^T partial += V_s^T P_s^T  (contraction over this wave's 16 keys)
#pragma unroll
        for (int dd = 0; dd < 4; ++dd)
#pragma unroll
            for (int nq = 0; nq < 4; ++nq)
                o_acc[dd][nq] = mfma16_bf16(vf[dd], pf[nq], o_acc[dd][nq]);
    }

    // ---- l merge: reduce across quads, publish per-wave totals
#pragma unroll
    for (int nq = 0; nq < 4; ++nq) {
        float v = l_part[nq];
        v += __shfl_xor(v, 16);
        v += __shfl_xor(v, 32);
        l_part[nq] = v;
    }
    if (lane < 16) {
#pragma unroll
        for (int nq = 0; nq < 4; ++nq) Lb[s][nq][lane] = l_part[nq];
    }
    __syncthreads();   // Lb ready; DMA stage free (all compute done)

    float inv[4];
#pragma unroll
    for (int nq = 0; nq < 4; ++nq)
        inv[nq] = 1.0f / (Lb[0][nq][lane15] + Lb[1][nq][lane15] +
                          Lb[2][nq][lane15] + Lb[3][nq][lane15]);

    // ---- O merge: pairwise tree per d-half (32 d), buffers [q 64][stride 36]
    float* Mf0 = (float*)&stage[0][0];
    float* Mf1 = Mf0 + 64 * 36;                  // 9216B each, 18.4KB of 32KB

#pragma unroll
    for (int dh = 0; dh < 2; ++dh) {
        if (s == 1 || s == 3) {
            float* Mf = (s == 1) ? Mf0 : Mf1;
#pragma unroll
            for (int c = 0; c < 2; ++c)
#pragma unroll
                for (int nq = 0; nq < 4; ++nq)
                    *(f32x4*)&Mf[(nq * 16 + lane15) * 36 + c * 16 + quad * 4] =
                        o_acc[dh * 2 + c][nq];
        }
        __syncthreads();
        if (s == 0 || s == 2) {
            const float* Mf = (s == 0) ? Mf0 : Mf1;
#pragma unroll
            for (int c = 0; c < 2; ++c)
#pragma unroll
                for (int nq = 0; nq < 4; ++nq)
                    o_acc[dh * 2 + c][nq] +=
                        *(const f32x4*)&Mf[(nq * 16 + lane15) * 36 + c * 16 + quad * 4];
        }
        __syncthreads();
        if (s == 2) {
#pragma unroll
            for (int c = 0; c < 2; ++c)
#pragma unroll
                for (int nq = 0; nq < 4; ++nq)
                    *(f32x4*)&Mf0[(nq * 16 + lane15) * 36 + c * 16 + quad * 4] =
                        o_acc[dh * 2 + c][nq];
        }
        __syncthreads();
        if (s == 0) {
            // final sum + normalize + publish to Mf1
#pragma unroll
            for (int c = 0; c < 2; ++c)
#pragma unroll
                for (int nq = 0; nq < 4; ++nq) {
                    f32x4 v = o_acc[dh * 2 + c][nq] +
                        *(const f32x4*)&Mf0[(nq * 16 + lane15) * 36 + c * 16 + quad * 4];
                    v *= inv[nq];
                    *(f32x4*)&Mf1[(nq * 16 + lane15) * 36 + c * 16 + quad * 4] = v;
                }
        }
        __syncthreads();
        // all waves store their 16 q rows of this 32-d half (coalesced 128B rows)
        {
            float* orow = out + ((size_t)(b * T_ + a * 64 + s * 16)) * C_ + h * 64 + dh * 32;
#pragma unroll
            for (int c = 0; c < 2; ++c) {
                const int idx = c * 64 + lane;   // 0..127
                const int tl  = idx >> 3;        // 0..15
                const int dc  = (idx & 7) * 4;   // 0..28
                float4 v = *(float4*)&Mf1[(s * 16 + tl) * 36 + dc];
                *(float4*)(orow + (size_t)tl * C_ + dc) = v;
            }
        }
        __syncthreads();   // before next d-half overwrites Mf
    }
}

// ---------------------------------------------------------------------------
// Launch
// ---------------------------------------------------------------------------
extern "C" void kernel_launch(void* const* d_in, const int* in_sizes, int n_in,
                              void* d_out, int out_size, void* d_ws, size_t ws_size,
                              hipStream_t stream) {
    const float* x  = (const float*)d_in[0];
    const float* Wq = (const float*)d_in[1];
    const float* bq = (const float*)d_in[2];
    const float* Wk = (const float*)d_in[3];
    const float* bk = (const float*)d_in[4];
    const float* Wv = (const float*)d_in[5];
    const float* bv = (const float*)d_in[6];
    float* out = (float*)d_out;

    unsigned short* xb  = (unsigned short*)d_ws;            // 4096*1024
    unsigned short* wb  = xb  + (size_t)B_ * T_ * C_;       // 3*1024*1024
    unsigned short* qb  = wb  + (size_t)3 * C_ * C_;        // chunk-tiled Q
    unsigned short* ktb = qb  + (size_t)B_ * H_ * T_ * D_;  // chunk-tiled K
    unsigned short* vtb = ktb + (size_t)B_ * H_ * T_ * D_;  // chunk-tiled V

    convert_all<<<7168, 256, 0, stream>>>(x, Wq, Wk, Wv, xb, wb);
    gemm_qkv<<<768, 256, 0, stream>>>(xb, wb, bq, bk, bv, qb, ktb, vtb);
    attn<<<1024, 256, 0, stream>>>(qb, ktb, vtb, out);
}